// Round 3
// baseline (652.724 us; speedup 1.0000x reference)
//
#include <hip/hip_runtime.h>
#include <math.h>
#include <stdint.h>

// GQA causal attention fwd, fp32 in/out, flash online-softmax, fp16 MFMA compute.
// B=2 HQ=32 HKV=8 S=2048 D=128. Mask is pure causal -> applied analytically.
//
// R3 changes vs R2 (which was stall-dominated: true pipe utilization ~10%, wall =
// longest-block serial chain 64 tiles x ~10.6k cyc latency):
//  1) 2-deep global prefetch pipeline: loads for tile t+2 issued at tile t
//     (two named reg sets, unrolled x2 loop), consumed at t+1's store ->
//     compiler emits counted vmcnt waits; ~2 iterations of latency budget
//     instead of an effective vmcnt(0) drain every tile.
//  2) Split-K (flash-decoding) for qb>=8: two chunks of 2qb+2<=32 tiles each.
//     Chunk0 writes unnormalized O into O; chunk1 writes partial O + (m,l) to
//     workspace; fa_combine merges. Gated on ws_size with silent fallback.
//  3) Dispatch mapping: entries sorted by descending tile count, head-innermost,
//     so the first co-residency generation contains all long chains.
//
// Compute core unchanged from R2 (verified): swapped QK^T (A=K, B=Q) -> S^T per
// wave; softmax in-lane + shfl_xor(32); PV as O^T = V^T P^T with P already in
// B-fragment layout; d-permuted fp16 LDS (one ds_read_b128 per MFMA A-frag);
// defer-max (T13).

#define B_    2
#define HQ_   32
#define HKV_  8
#define S_    2048
#define D_    128
#define KT_   32
#define THREADS_ 256
#define RPB_  128
#define SL2E_ 0.12751743f     // (1/sqrt(128)) * log2(e)  -> softmax in exp2 domain
#define NEGBIG_ -3.0e38f
#define KLD_  136             // K row pitch in fp16 elems (128 + 8 pad, 16B-mult)
#define VLD_  40              // V^T row pitch in fp16 elems (32 + 8 pad, 16B-mult)
#define DEFER_THR_ 8.0f
#define NSLOT_ 512            // 64 heads x 8 split qb (qb 8..15)

typedef _Float16 v4h  __attribute__((ext_vector_type(4)));
typedef _Float16 v8h  __attribute__((ext_vector_type(8)));
typedef float    f32x16 __attribute__((ext_vector_type(16)));

// Entry tables (split mode): 24 entries/head, descending tile count.
// qb 0..7 unsplit (4qb+4 tiles); qb 8..15 split into 2 chunks (2qb+2 tiles each).
__constant__ int eqb_[24] = {15,15,7,14,14,13,13,6,12,12,11,11,5,10,10,9,9,4,8,8,3,2,1,0};
__constant__ int ech_[24] = { 0, 1,0, 0, 1, 0, 1,0, 0, 1, 0, 1,0, 0, 1,0,1,0,0,1,0,0,0,0};
__constant__ int enc_[24] = { 2, 2,1, 2, 2, 2, 2,1, 2, 2, 2, 2,1, 2, 2,2,2,1,2,2,1,1,1,1};

__device__ __forceinline__ void load_k(const float4* kb4, int k0, int tid, float4 (&kr)[4]) {
    #pragma unroll
    for (int p = 0; p < 4; ++p)
        kr[p] = kb4[(size_t)(k0 + p * 8 + (tid >> 5)) * 32 + (tid & 31)];
}

__device__ __forceinline__ void load_v(const float4* vb4, int k0, int tid, float4 (&vr)[4]) {
    #pragma unroll
    for (int p = 0; p < 4; ++p)
        vr[p] = vb4[(size_t)(k0 + p * 8 + (tid & 7)) * (HKV_ * 32) + (tid >> 3)];
}

// regs -> LDS: K row-major [32][KLD_], V transposed [128][VLD_], fp16, d-permuted
// within each 16-group ([0,2,1,3] quads) so MFMA fragments read as single b128.
__device__ __forceinline__ void store_kv(int tid, const float4 (&kr)[4], const float4 (&vr)[4],
                                         _Float16* kh, _Float16* vh) {
    const int qi  = tid & 3;
    const int c31 = tid & 31;
    const int d0p = ((c31 >> 2) << 4) | ((((c31 & 1) << 1) | ((c31 >> 1) & 1)) << 2);
    #pragma unroll
    for (int p = 0; p < 4; ++p) {
        {   // ---- K: lane covers (key = p*8 + tid>>5, d-group = tid&31) ----
            const int key = p * 8 + (tid >> 5);
            const float4 f = kr[p];
            v4h hv = {(_Float16)f.x, (_Float16)f.y, (_Float16)f.z, (_Float16)f.w};
            *(v4h*)&kh[key * KLD_ + d0p] = hv;
        }
        {   // ---- V: quad 4x4 transpose, then write 4 consecutive keys of one d-row ----
            float a0 = vr[p].x, a1 = vr[p].y, a2 = vr[p].z, a3 = vr[p].w;
            float t, r;
            t = (qi & 1) ? a0 : a1; r = __shfl_xor(t, 1);
            if (qi & 1) a0 = r; else a1 = r;
            t = (qi & 1) ? a2 : a3; r = __shfl_xor(t, 1);
            if (qi & 1) a2 = r; else a3 = r;
            t = (qi & 2) ? a0 : a2; r = __shfl_xor(t, 2);
            if (qi & 2) a0 = r; else a2 = r;
            t = (qi & 2) ? a1 : a3; r = __shfl_xor(t, 2);
            if (qi & 2) a1 = r; else a3 = r;
            const int drow = (tid >> 3) * 4 + qi;
            const int kq   = p * 8 + (tid & 4);
            const int kqp  = (kq & 16) | (((((kq >> 2) & 1) << 1) | ((kq >> 3) & 1)) << 2);
            v4h hv = {(_Float16)a0, (_Float16)a1, (_Float16)a2, (_Float16)a3};
            *(v4h*)&vh[drow * VLD_ + kqp] = hv;
        }
    }
}

__device__ __forceinline__ void compute_tile(
    const _Float16* khb, const _Float16* vhb,
    const v8h (&qh)[8], f32x16 (&oacc)[4],
    float& m, float& lsum,
    int lane, int hig, int qloc, bool active, bool diag)
{
    if (!active) return;
    // ---- QK^T: S^T = K * Q^T, 8 k-steps, one b128 A-read per MFMA ----
    const int koff = (lane & 31) * KLD_ + 8 * hig;
    f32x16 sacc[2];
    #pragma unroll
    for (int cch = 0; cch < 2; ++cch)
        #pragma unroll
        for (int j = 0; j < 16; ++j) sacc[cch][j] = 0.f;
    #pragma unroll
    for (int ks = 0; ks < 8; ++ks) {
        v8h ka = *(const v8h*)&khb[koff + ks * 16];
        sacc[ks & 1] = __builtin_amdgcn_mfma_f32_32x32x16_f16(ka, qh[ks], sacc[ks & 1], 0, 0, 0);
    }
    float sv[16];
    #pragma unroll
    for (int j = 0; j < 16; ++j) sv[j] = sacc[0][j] + sacc[1][j];

    // ---- causal mask (diagonal tile only); tile base == row-tile base there ----
    if (diag) {
        #pragma unroll
        for (int j = 0; j < 16; ++j) {
            const int key = (j & 3) + 8 * (j >> 2) + 4 * hig;
            if (key > qloc) sv[j] = NEGBIG_;
        }
    }
    // ---- online softmax: in-lane over 16 + shfl_xor(32), defer-max ----
    float mt = NEGBIG_;
    #pragma unroll
    for (int j = 0; j < 16; ++j) mt = fmaxf(mt, sv[j]);
    mt = fmaxf(mt, __shfl_xor(mt, 32));
    if (__any(mt > m + DEFER_THR_)) {
        const float mn = fmaxf(m, mt);
        const float al = exp2f(m - mn);
        m = mn;
        lsum *= al;
        #pragma unroll
        for (int d = 0; d < 4; ++d)
            #pragma unroll
            for (int j = 0; j < 16; ++j) oacc[d][j] *= al;
    }
    float ps = 0.f;
    #pragma unroll
    for (int j = 0; j < 16; ++j) {
        const float p = exp2f(sv[j] - m);   // bounded by 2^DEFER_THR_
        sv[j] = p;
        ps += p;
    }
    ps += __shfl_xor(ps, 32);
    lsum += ps;

    // ---- P -> fp16 B-fragments (elems j = acc regs 8h+j) ----
    v8h ph0, ph1;
    #pragma unroll
    for (int j = 0; j < 8; ++j) {
        ph0[j] = (_Float16)sv[j];
        ph1[j] = (_Float16)sv[8 + j];
    }
    // ---- PV: O^T += V^T * P^T, 4 d-subtiles x 2 key-halves ----
    const int voff = (lane & 31) * VLD_ + 8 * hig;
    #pragma unroll
    for (int d = 0; d < 4; ++d) {
        #pragma unroll
        for (int h2 = 0; h2 < 2; ++h2) {
            v8h va = *(const v8h*)&vhb[d * 32 * VLD_ + voff + h2 * 16];
            oacc[d] = __builtin_amdgcn_mfma_f32_32x32x16_f16(va, h2 ? ph1 : ph0, oacc[d], 0, 0, 0);
        }
    }
}

__global__ __launch_bounds__(THREADS_, 3)
void fa_fwd(const float* __restrict__ Q, const float* __restrict__ K,
            const float* __restrict__ V, float* __restrict__ O,
            float* __restrict__ wsO, float* __restrict__ wsMl, int split) {
    __shared__ _Float16 KHI[2][KT_ * KLD_];   // 2 x 8704 B
    __shared__ _Float16 VHI[2][D_ * VLD_];    // 2 x 10240 B  -> total 37888 B

    const int tid  = threadIdx.x;
    const int lane = tid & 63;
    const int w    = tid >> 6;      // wave 0..3
    const int hig  = lane >> 5;     // MFMA k-group
    const int qloc = lane & 31;     // q column within wave's 32-row tile

    const int bx   = blockIdx.x;
    const int head = bx & 63;       // head-innermost: equal-length blocks adjacent
    const int e    = bx >> 6;
    int qb, ch, nc;
    if (split) { qb = eqb_[e]; ch = ech_[e]; nc = enc_[e]; }
    else       { qb = 15 - e;  ch = 0;       nc = 1; }

    const int b    = head >> 5;
    const int hq   = head & 31;
    const int hkv  = hq >> 2;       // N_REP = 4
    const int nt   = (nc == 1) ? (4 * qb + 4) : (2 * qb + 2);   // always even
    const int gt0  = ch * nt;       // global tile offset of this chunk
    const int base = qb * RPB_;
    const int row  = base + w * 32 + qloc;
    const int dgt  = 4 * qb + w;    // wave's diagonal global tile

    const float4* kb4 = (const float4*)K + (size_t)(b * HKV_ + hkv) * S_ * 32;
    const float4* vb4 = (const float4*)V + (size_t)b * S_ * HKV_ * 32 + hkv * 32;
    const float4* qg  = (const float4*)Q + ((size_t)(b * HQ_ + hq) * S_ + row) * 32;

    // ---- Q fragments: pre-scaled by SL2E_, fp16, hoisted (B-operand) ----
    v8h qh[8];
    #pragma unroll
    for (int ks = 0; ks < 8; ++ks) {
        float4 f0 = qg[ks * 4 + hig];
        float4 f1 = qg[ks * 4 + 2 + hig];
        v8h qv = {(_Float16)(f0.x * SL2E_), (_Float16)(f0.y * SL2E_),
                  (_Float16)(f0.z * SL2E_), (_Float16)(f0.w * SL2E_),
                  (_Float16)(f1.x * SL2E_), (_Float16)(f1.y * SL2E_),
                  (_Float16)(f1.z * SL2E_), (_Float16)(f1.w * SL2E_)};
        qh[ks] = qv;
    }

    f32x16 oacc[4];
    #pragma unroll
    for (int d = 0; d < 4; ++d)
        #pragma unroll
        for (int j = 0; j < 16; ++j) oacc[d][j] = 0.f;
    float m = NEGBIG_, lsum = 0.f;

    // ---- 2-deep prefetch pipeline: named reg sets A/B (no runtime indexing) ----
    float4 krA[4], vrA[4], krB[4], vrB[4];
    #define KOF_(t) ((gt0 + (((t) < nt) ? (t) : (nt - 1))) * KT_)
    load_k(kb4, KOF_(0), tid, krA); load_v(vb4, KOF_(0), tid, vrA);
    load_k(kb4, KOF_(1), tid, krB); load_v(vb4, KOF_(1), tid, vrB);
    store_kv(tid, krA, vrA, KHI[0], VHI[0]);
    __syncthreads();

    for (int t = 0; t < nt; t += 2) {
        // -- even tile t: compute buf0; store tile t+1 (B regs); load tile t+2 -> A --
        load_k(kb4, KOF_(t + 2), tid, krA); load_v(vb4, KOF_(t + 2), tid, vrA);
        {
            const int gt = gt0 + t;
            compute_tile(KHI[0], VHI[0], qh, oacc, m, lsum, lane, hig, qloc,
                         gt <= dgt, gt == dgt);
        }
        store_kv(tid, krB, vrB, KHI[1], VHI[1]);
        __syncthreads();
        // -- odd tile t+1: compute buf1; store tile t+2 (A regs); load tile t+3 -> B --
        load_k(kb4, KOF_(t + 3), tid, krB); load_v(vb4, KOF_(t + 3), tid, vrB);
        {
            const int gt = gt0 + t + 1;
            compute_tile(KHI[1], VHI[1], qh, oacc, m, lsum, lane, hig, qloc,
                         gt <= dgt, gt == dgt);
        }
        if (t + 2 < nt) {
            store_kv(tid, krA, vrA, KHI[0], VHI[0]);
        }
        __syncthreads();
    }
    #undef KOF_

    // ---- epilogue ----
    float inv;
    float4* og;
    if (nc == 1) {
        inv = 1.0f / lsum;
        og  = (float4*)O + ((size_t)(b * HQ_ + hq) * S_ + row) * 32;
    } else {
        const int slot = head * 8 + (qb - 8);
        const int rl   = w * 32 + qloc;
        if (lane < 32) {   // lanes 32..63 hold duplicates
            float* mlp = wsMl + (ch ? (size_t)NSLOT_ * RPB_ * 2 : 0)
                       + (size_t)slot * RPB_ * 2 + (size_t)rl * 2;
            *(float2*)mlp = make_float2(m, lsum);
        }
        inv = 1.0f;   // unnormalized partial
        og  = ch ? ((float4*)wsO + ((size_t)slot * RPB_ + rl) * 32)
                 : ((float4*)O + ((size_t)(b * HQ_ + hq) * S_ + row) * 32);
    }
    #pragma unroll
    for (int d = 0; d < 4; ++d) {
        #pragma unroll
        for (int rq = 0; rq < 4; ++rq) {
            float4 st;
            st.x = oacc[d][4 * rq + 0] * inv;
            st.y = oacc[d][4 * rq + 1] * inv;
            st.z = oacc[d][4 * rq + 2] * inv;
            st.w = oacc[d][4 * rq + 3] * inv;
            og[d * 8 + rq * 2 + hig] = st;
        }
    }
}

// Merge chunk0 (unnormalized, in O) with chunk1 (in wsO) for split slots.
__global__ __launch_bounds__(256)
void fa_combine(float* __restrict__ O, const float* __restrict__ wsO,
                const float* __restrict__ wsMl) {
    const int slot = blockIdx.x;
    const int head = slot >> 3;
    const int qb   = 8 + (slot & 7);
    const int b    = head >> 5, hq = head & 31;
    const int tid  = threadIdx.x;

    __shared__ float4 mlsh[RPB_];   // (mA, lA, mB, lB) per row
    if (tid < RPB_) {
        const float2 a = *(const float2*)(wsMl + (size_t)slot * RPB_ * 2 + (size_t)tid * 2);
        const float2 c = *(const float2*)(wsMl + (size_t)NSLOT_ * RPB_ * 2
                                          + (size_t)slot * RPB_ * 2 + (size_t)tid * 2);
        mlsh[tid] = make_float4(a.x, a.y, c.x, c.y);
    }
    __syncthreads();

    const float4* pB = (const float4*)wsO + (size_t)slot * RPB_ * 32;
    float4* pO = (float4*)O + ((size_t)(b * HQ_ + hq) * S_ + (size_t)qb * RPB_) * 32;
    #pragma unroll
    for (int i = 0; i < 16; ++i) {
        const int idx = tid + 256 * i;            // rows x 32 float4
        const float4 c = mlsh[idx >> 5];
        const float mm = fmaxf(c.x, c.z);
        float aA = exp2f(c.x - mm), aB = exp2f(c.z - mm);
        const float inv = 1.0f / (aA * c.y + aB * c.w);
        aA *= inv; aB *= inv;
        const float4 oa = pO[idx];
        const float4 ob = pB[idx];
        float4 r;
        r.x = aA * oa.x + aB * ob.x;
        r.y = aA * oa.y + aB * ob.y;
        r.z = aA * oa.z + aB * ob.z;
        r.w = aA * oa.w + aB * ob.w;
        pO[idx] = r;
    }
}

extern "C" void kernel_launch(void* const* d_in, const int* in_sizes, int n_in,
                              void* d_out, int out_size, void* d_ws, size_t ws_size,
                              hipStream_t stream) {
    const float* Q = (const float*)d_in[0];   // [B,HQ,S,D]
    const float* K = (const float*)d_in[1];   // [B,HKV,S,D]
    const float* V = (const float*)d_in[2];   // [B,S,Hkv,D]
    // d_in[3] (attention_mask) unused: pure causal, applied in-kernel.
    float* O = (float*)d_out;                 // [B,HQ,S,D]

    const size_t WSO_F  = (size_t)NSLOT_ * RPB_ * D_;   // chunk1 partial O (fp32)
    const size_t WSML_F = (size_t)NSLOT_ * RPB_ * 2;    // (m,l) per chunk
    const size_t needB  = (WSO_F + 2 * WSML_F) * sizeof(float);   // ~34.6 MB
    const int split = (d_ws != nullptr && ws_size >= needB) ? 1 : 0;
    float* wsO  = (float*)d_ws;
    float* wsMl = wsO + WSO_F;

    const int nblocks = (split ? 24 : 16) * (B_ * HQ_);   // 1536 or 1024
    fa_fwd<<<dim3(nblocks), dim3(THREADS_), 0, stream>>>(Q, K, V, O, wsO, wsMl, split);
    if (split)
        fa_combine<<<dim3(NSLOT_), dim3(256), 0, stream>>>(O, wsO, wsMl);
}

// Round 5
// 635.620 us; speedup vs baseline: 1.0269x; 1.0269x over previous
//
#include <hip/hip_runtime.h>
#include <math.h>
#include <stdint.h>

// GQA causal attention fwd, fp32 in/out, flash online-softmax, fp16 MFMA compute.
// B=2 HQ=32 HKV=8 S=2048 D=128. Mask is pure causal -> applied analytically.
//
// R5 == R4 resubmission (R4 bench failed on infra: container acquire, no kernel
// error). R4 = R2 (283 us) + 2-deep prefetch pipeline + s_setprio around MFMA,
// with R2's locality-preserving dispatch order RESTORED and split-K REMOVED.
// R3 post-mortem: head-innermost order + split-K destroyed K/V L2 temporal
// locality (FETCH 291MB -> 1.18GB; dur == bytes / 3.3TB/s, L2-miss-path-bound).
// Locality requires: blocks of the same head adjacent AND all blocks walking
// K/V tiles from 0 in rough lockstep -> R2's chunk sets {i,15-i,4+i,11-i}.
//
// Compute core (verified R2): swapped QK^T (A=K, B=Q) -> S^T per wave; lane owns
// q=lane&31, 16 score regs at key=(reg&3)+8*(reg>>2)+4*(lane>>5); softmax
// in-lane + shfl_xor(32); PV as O^T = V^T P^T with P already in B-fragment
// layout; d-permuted fp16 LDS (one ds_read_b128 per MFMA A-frag); defer-max.
//
// 2-deep pipeline: named reg sets A/B (no runtime indexing -> no scratch).
// Loads for tile t+2 issued at top of tile t's phase, consumed by store_kv
// after the NEXT barrier -> compiler emits counted vmcnt; ~2 compute phases of
// global-latency cover (vs same-iteration vmcnt drain in R2).

#define B_    2
#define HQ_   32
#define HKV_  8
#define S_    2048
#define D_    128
#define KT_   32
#define THREADS_ 256
#define RPB_  128
#define SL2E_ 0.12751743f     // (1/sqrt(128)) * log2(e)  -> softmax in exp2 domain
#define NEGBIG_ -3.0e38f
#define KLD_  136             // K row pitch in fp16 elems (128 + 8 pad, 16B-mult)
#define VLD_  40              // V^T row pitch in fp16 elems (32 + 8 pad, 16B-mult)
#define DEFER_THR_ 8.0f

typedef _Float16 v4h  __attribute__((ext_vector_type(4)));
typedef _Float16 v8h  __attribute__((ext_vector_type(8)));
typedef float    f32x16 __attribute__((ext_vector_type(16)));

__device__ __forceinline__ void load_k(const float4* kb4, int k0, int tid, float4 (&kr)[4]) {
    #pragma unroll
    for (int p = 0; p < 4; ++p)
        kr[p] = kb4[(size_t)(k0 + p * 8 + (tid >> 5)) * 32 + (tid & 31)];
}

__device__ __forceinline__ void load_v(const float4* vb4, int k0, int tid, float4 (&vr)[4]) {
    #pragma unroll
    for (int p = 0; p < 4; ++p)
        vr[p] = vb4[(size_t)(k0 + p * 8 + (tid & 7)) * (HKV_ * 32) + (tid >> 3)];
}

// regs -> LDS: K row-major [32][KLD_], V transposed [128][VLD_], fp16, d-permuted
// within each 16-group ([0,2,1,3] quads) so MFMA fragments read as single b128.
__device__ __forceinline__ void store_kv(int tid, const float4 (&kr)[4], const float4 (&vr)[4],
                                         _Float16* kh, _Float16* vh) {
    const int qi  = tid & 3;
    const int c31 = tid & 31;
    const int d0p = ((c31 >> 2) << 4) | ((((c31 & 1) << 1) | ((c31 >> 1) & 1)) << 2);
    #pragma unroll
    for (int p = 0; p < 4; ++p) {
        {   // ---- K: lane covers (key = p*8 + tid>>5, d-group = tid&31) ----
            const int key = p * 8 + (tid >> 5);
            const float4 f = kr[p];
            v4h hv = {(_Float16)f.x, (_Float16)f.y, (_Float16)f.z, (_Float16)f.w};
            *(v4h*)&kh[key * KLD_ + d0p] = hv;
        }
        {   // ---- V: quad 4x4 transpose, then write 4 consecutive keys of one d-row ----
            float a0 = vr[p].x, a1 = vr[p].y, a2 = vr[p].z, a3 = vr[p].w;
            float t, r;
            t = (qi & 1) ? a0 : a1; r = __shfl_xor(t, 1);
            if (qi & 1) a0 = r; else a1 = r;
            t = (qi & 1) ? a2 : a3; r = __shfl_xor(t, 1);
            if (qi & 1) a2 = r; else a3 = r;
            t = (qi & 2) ? a0 : a2; r = __shfl_xor(t, 2);
            if (qi & 2) a0 = r; else a2 = r;
            t = (qi & 2) ? a1 : a3; r = __shfl_xor(t, 2);
            if (qi & 2) a1 = r; else a3 = r;
            const int drow = (tid >> 3) * 4 + qi;
            const int kq   = p * 8 + (tid & 4);
            const int kqp  = (kq & 16) | (((((kq >> 2) & 1) << 1) | ((kq >> 3) & 1)) << 2);
            v4h hv = {(_Float16)a0, (_Float16)a1, (_Float16)a2, (_Float16)a3};
            *(v4h*)&vh[drow * VLD_ + kqp] = hv;
        }
    }
}

__device__ __forceinline__ void compute_tile(
    const _Float16* khb, const _Float16* vhb,
    const v8h (&qh)[8], f32x16 (&oacc)[4],
    float& m, float& lsum,
    int lane, int hig, int qloc, bool active, bool diag)
{
    if (!active) return;
    // ---- QK^T: S^T = K * Q^T, 8 k-steps, one b128 A-read per MFMA ----
    const int koff = (lane & 31) * KLD_ + 8 * hig;
    f32x16 sacc[2];
    #pragma unroll
    for (int cch = 0; cch < 2; ++cch)
        #pragma unroll
        for (int j = 0; j < 16; ++j) sacc[cch][j] = 0.f;
    __builtin_amdgcn_s_setprio(1);
    #pragma unroll
    for (int ks = 0; ks < 8; ++ks) {
        v8h ka = *(const v8h*)&khb[koff + ks * 16];
        sacc[ks & 1] = __builtin_amdgcn_mfma_f32_32x32x16_f16(ka, qh[ks], sacc[ks & 1], 0, 0, 0);
    }
    __builtin_amdgcn_s_setprio(0);
    float sv[16];
    #pragma unroll
    for (int j = 0; j < 16; ++j) sv[j] = sacc[0][j] + sacc[1][j];

    // ---- causal mask (diagonal tile only) ----
    if (diag) {
        #pragma unroll
        for (int j = 0; j < 16; ++j) {
            const int key = (j & 3) + 8 * (j >> 2) + 4 * hig;
            if (key > qloc) sv[j] = NEGBIG_;
        }
    }
    // ---- online softmax: in-lane over 16 + shfl_xor(32), defer-max ----
    float mt = NEGBIG_;
    #pragma unroll
    for (int j = 0; j < 16; ++j) mt = fmaxf(mt, sv[j]);
    mt = fmaxf(mt, __shfl_xor(mt, 32));
    if (__any(mt > m + DEFER_THR_)) {
        const float mn = fmaxf(m, mt);
        const float al = exp2f(m - mn);
        m = mn;
        lsum *= al;
        #pragma unroll
        for (int d = 0; d < 4; ++d)
            #pragma unroll
            for (int j = 0; j < 16; ++j) oacc[d][j] *= al;
    }
    float ps = 0.f;
    #pragma unroll
    for (int j = 0; j < 16; ++j) {
        const float p = exp2f(sv[j] - m);   // bounded by 2^DEFER_THR_
        sv[j] = p;
        ps += p;
    }
    ps += __shfl_xor(ps, 32);
    lsum += ps;

    // ---- P -> fp16 B-fragments (elems j = acc regs 8h+j) ----
    v8h ph0, ph1;
    #pragma unroll
    for (int j = 0; j < 8; ++j) {
        ph0[j] = (_Float16)sv[j];
        ph1[j] = (_Float16)sv[8 + j];
    }
    // ---- PV: O^T += V^T * P^T, 4 d-subtiles x 2 key-halves ----
    const int voff = (lane & 31) * VLD_ + 8 * hig;
    __builtin_amdgcn_s_setprio(1);
    #pragma unroll
    for (int d = 0; d < 4; ++d) {
        #pragma unroll
        for (int h2 = 0; h2 < 2; ++h2) {
            v8h va = *(const v8h*)&vhb[d * 32 * VLD_ + voff + h2 * 16];
            oacc[d] = __builtin_amdgcn_mfma_f32_32x32x16_f16(va, h2 ? ph1 : ph0, oacc[d], 0, 0, 0);
        }
    }
    __builtin_amdgcn_s_setprio(0);
}

__global__ __launch_bounds__(THREADS_, 3)
void fa_fwd(const float* __restrict__ Q, const float* __restrict__ K,
            const float* __restrict__ V, float* __restrict__ O) {
    __shared__ _Float16 KHI[2][KT_ * KLD_];   // 2 x 8704 B
    __shared__ _Float16 VHI[2][D_ * VLD_];    // 2 x 10240 B  -> total 37888 B

    const int tid  = threadIdx.x;
    const int lane = tid & 63;
    const int w    = tid >> 6;      // wave 0..3
    const int hig  = lane >> 5;     // MFMA k-group
    const int qloc = lane & 31;     // q column within wave's 32-row tile

    // R2 load-balance swizzle: 4 same-head blocks adjacent (K/V L2 co-walk);
    // chunk sets {i,15-i,4+i,11-i} keep per-generation totals ~constant.
    const int bx = blockIdx.x;
    const int cc = bx & 255, chunk = bx >> 8;
    const int head = cc >> 2, i4 = cc & 3;
    int qb;
    if      (chunk == 0) qb = i4;
    else if (chunk == 1) qb = 15 - i4;
    else if (chunk == 2) qb = 4 + i4;
    else                 qb = 11 - i4;

    const int b    = head >> 5;
    const int hq   = head & 31;
    const int hkv  = hq >> 2;       // N_REP = 4
    const int base = qb * RPB_;
    const int row  = base + w * 32 + qloc;
    const int nt   = 4 * qb + 4;    // tile count (always even)
    const int diagt = 4 * qb + w;   // wave's diagonal tile index

    const float4* kb4 = (const float4*)K + (size_t)(b * HKV_ + hkv) * S_ * 32;
    const float4* vb4 = (const float4*)V + (size_t)b * S_ * HKV_ * 32 + hkv * 32;
    const float4* qg  = (const float4*)Q + ((size_t)(b * HQ_ + hq) * S_ + row) * 32;

    // ---- Q fragments: pre-scaled by SL2E_, fp16, hoisted (B-operand) ----
    v8h qh[8];
    #pragma unroll
    for (int ks = 0; ks < 8; ++ks) {
        float4 f0 = qg[ks * 4 + hig];
        float4 f1 = qg[ks * 4 + 2 + hig];
        v8h qv = {(_Float16)(f0.x * SL2E_), (_Float16)(f0.y * SL2E_),
                  (_Float16)(f0.z * SL2E_), (_Float16)(f0.w * SL2E_),
                  (_Float16)(f1.x * SL2E_), (_Float16)(f1.y * SL2E_),
                  (_Float16)(f1.z * SL2E_), (_Float16)(f1.w * SL2E_)};
        qh[ks] = qv;
    }

    f32x16 oacc[4];
    #pragma unroll
    for (int d = 0; d < 4; ++d)
        #pragma unroll
        for (int j = 0; j < 16; ++j) oacc[d][j] = 0.f;
    float m = NEGBIG_, lsum = 0.f;

    // ---- 2-deep prefetch pipeline: named reg sets A/B (no runtime indexing) ----
    float4 krA[4], vrA[4], krB[4], vrB[4];
    #define KOF_(t) ((((t) < nt) ? (t) : (nt - 1)) * KT_)
    load_k(kb4, KOF_(0), tid, krA); load_v(vb4, KOF_(0), tid, vrA);
    load_k(kb4, KOF_(1), tid, krB); load_v(vb4, KOF_(1), tid, vrB);
    store_kv(tid, krA, vrA, KHI[0], VHI[0]);
    __syncthreads();

    for (int t = 0; t < nt; t += 2) {
        // -- even tile t: load t+2 -> A; compute buf0; store t+1 (B regs) --
        load_k(kb4, KOF_(t + 2), tid, krA); load_v(vb4, KOF_(t + 2), tid, vrA);
        compute_tile(KHI[0], VHI[0], qh, oacc, m, lsum, lane, hig, qloc,
                     t <= diagt, t == diagt);
        store_kv(tid, krB, vrB, KHI[1], VHI[1]);
        __syncthreads();
        // -- odd tile t+1: load t+3 -> B; compute buf1; store t+2 (A regs) --
        load_k(kb4, KOF_(t + 3), tid, krB); load_v(vb4, KOF_(t + 3), tid, vrB);
        compute_tile(KHI[1], VHI[1], qh, oacc, m, lsum, lane, hig, qloc,
                     t + 1 <= diagt, t + 1 == diagt);
        if (t + 2 < nt) {
            store_kv(tid, krA, vrA, KHI[0], VHI[0]);
        }
        __syncthreads();
    }
    #undef KOF_

    // ---- epilogue: O^T frag -> O[q][d], 4 consecutive d per reg-quad ----
    const float inv = 1.0f / lsum;
    float4* og = (float4*)O + ((size_t)(b * HQ_ + hq) * S_ + row) * 32;
    #pragma unroll
    for (int d = 0; d < 4; ++d) {
        #pragma unroll
        for (int rq = 0; rq < 4; ++rq) {
            float4 st;
            st.x = oacc[d][4 * rq + 0] * inv;
            st.y = oacc[d][4 * rq + 1] * inv;
            st.z = oacc[d][4 * rq + 2] * inv;
            st.w = oacc[d][4 * rq + 3] * inv;
            og[d * 8 + rq * 2 + hig] = st;
        }
    }
}

extern "C" void kernel_launch(void* const* d_in, const int* in_sizes, int n_in,
                              void* d_out, int out_size, void* d_ws, size_t ws_size,
                              hipStream_t stream) {
    const float* Q = (const float*)d_in[0];   // [B,HQ,S,D]
    const float* K = (const float*)d_in[1];   // [B,HKV,S,D]
    const float* V = (const float*)d_in[2];   // [B,S,Hkv,D]
    // d_in[3] (attention_mask) unused: pure causal, applied in-kernel.
    float* O = (float*)d_out;                 // [B,HQ,S,D]

    const int nblocks = (S_ / RPB_) * (B_ * HQ_);  // 16 * 64 = 1024
    fa_fwd<<<dim3(nblocks), dim3(THREADS_), 0, stream>>>(Q, K, V, O);
}

// Round 6
// 378.621 us; speedup vs baseline: 1.7239x; 1.6788x over previous
//
#include <hip/hip_runtime.h>
#include <math.h>
#include <stdint.h>

// GQA causal attention fwd, fp32 in/out, flash online-softmax, fp16 MFMA compute.
// B=2 HQ=32 HKV=8 S=2048 D=128. Mask is pure causal -> applied analytically.
//
// R6 = exact R2 structure (283 us, verified) + XCD-aware block mapping + setprio.
// R5 post-mortem: the 2-deep prefetch pipeline DESTROYED L2 locality with the
// SAME dispatch order as R2 (FETCH 291->923 MB): R2's same-iteration
// load->consume chain is a latency governor that keeps same-head co-walker
// blocks in lockstep; decoupled prefetch let them drift past the ~4MB/XCD
// eviction horizon. So: 1-deep staging RESTORED (loads issued at iteration top,
// consumed by store_kv after compute, one barrier per tile).
//
// New in R6: within each 256-block chunk, bid = x + 8*(r + 4*i4 + 16*g) where
// kv-group kg = b*8+hkv, x = kg&7, g = kg>>3, r = hq&3. Round-robin XCD
// dispatch (bid%8) then places all 16 blocks sharing one K/V stream on ONE
// XCD; each XCD holds 2 kv-groups = 4 MB K/V ~= its private L2. Co-walkers
// share L2 lines instead of only the LLC.
//
// Compute core (verified R2): swapped QK^T (A=K, B=Q) -> S^T per wave; lane owns
// q=lane&31, 16 score regs at key=(reg&3)+8*(reg>>2)+4*(lane>>5); softmax
// in-lane + shfl_xor(32); PV as O^T = V^T P^T with P already in B-fragment
// layout; d-permuted fp16 LDS (one ds_read_b128 per MFMA A-frag); defer-max.
// s_setprio(1/0) around MFMA clusters (T5; SIMD arbitration only).

#define B_    2
#define HQ_   32
#define HKV_  8
#define S_    2048
#define D_    128
#define KT_   32
#define THREADS_ 256
#define RPB_  128
#define SL2E_ 0.12751743f     // (1/sqrt(128)) * log2(e)  -> softmax in exp2 domain
#define NEGBIG_ -3.0e38f
#define KLD_  136             // K row pitch in fp16 elems (128 + 8 pad, 16B-mult)
#define VLD_  40              // V^T row pitch in fp16 elems (32 + 8 pad, 16B-mult)
#define DEFER_THR_ 8.0f

typedef _Float16 v4h  __attribute__((ext_vector_type(4)));
typedef _Float16 v8h  __attribute__((ext_vector_type(8)));
typedef float    f32x16 __attribute__((ext_vector_type(16)));

__device__ __forceinline__ void load_k(const float4* kb4, int k0, int tid, float4 (&kr)[4]) {
    #pragma unroll
    for (int p = 0; p < 4; ++p)
        kr[p] = kb4[(size_t)(k0 + p * 8 + (tid >> 5)) * 32 + (tid & 31)];
}

__device__ __forceinline__ void load_v(const float4* vb4, int k0, int tid, float4 (&vr)[4]) {
    #pragma unroll
    for (int p = 0; p < 4; ++p)
        vr[p] = vb4[(size_t)(k0 + p * 8 + (tid & 7)) * (HKV_ * 32) + (tid >> 3)];
}

// regs -> LDS: K row-major [32][KLD_], V transposed [128][VLD_], fp16, d-permuted
// within each 16-group ([0,2,1,3] quads) so MFMA fragments read as single b128.
__device__ __forceinline__ void store_kv(int tid, const float4 (&kr)[4], const float4 (&vr)[4],
                                         _Float16* kh, _Float16* vh) {
    const int qi  = tid & 3;
    const int c31 = tid & 31;
    const int d0p = ((c31 >> 2) << 4) | ((((c31 & 1) << 1) | ((c31 >> 1) & 1)) << 2);
    #pragma unroll
    for (int p = 0; p < 4; ++p) {
        {   // ---- K: lane covers (key = p*8 + tid>>5, d-group = tid&31) ----
            const int key = p * 8 + (tid >> 5);
            const float4 f = kr[p];
            v4h hv = {(_Float16)f.x, (_Float16)f.y, (_Float16)f.z, (_Float16)f.w};
            *(v4h*)&kh[key * KLD_ + d0p] = hv;
        }
        {   // ---- V: quad 4x4 transpose, then write 4 consecutive keys of one d-row ----
            float a0 = vr[p].x, a1 = vr[p].y, a2 = vr[p].z, a3 = vr[p].w;
            float t, r;
            t = (qi & 1) ? a0 : a1; r = __shfl_xor(t, 1);
            if (qi & 1) a0 = r; else a1 = r;
            t = (qi & 1) ? a2 : a3; r = __shfl_xor(t, 1);
            if (qi & 1) a2 = r; else a3 = r;
            t = (qi & 2) ? a0 : a2; r = __shfl_xor(t, 2);
            if (qi & 2) a0 = r; else a2 = r;
            t = (qi & 2) ? a1 : a3; r = __shfl_xor(t, 2);
            if (qi & 2) a1 = r; else a3 = r;
            const int drow = (tid >> 3) * 4 + qi;
            const int kq   = p * 8 + (tid & 4);
            const int kqp  = (kq & 16) | (((((kq >> 2) & 1) << 1) | ((kq >> 3) & 1)) << 2);
            v4h hv = {(_Float16)a0, (_Float16)a1, (_Float16)a2, (_Float16)a3};
            *(v4h*)&vh[drow * VLD_ + kqp] = hv;
        }
    }
}

__global__ __launch_bounds__(THREADS_, 3)
void fa_fwd(const float* __restrict__ Q, const float* __restrict__ K,
            const float* __restrict__ V, float* __restrict__ O) {
    __shared__ _Float16 KHI[2][KT_ * KLD_];   // 2 x 8704 B
    __shared__ _Float16 VHI[2][D_ * VLD_];    // 2 x 10240 B  -> total 37888 B

    const int tid  = threadIdx.x;
    const int lane = tid & 63;
    const int w    = tid >> 6;      // wave 0..3
    const int hig  = lane >> 5;     // MFMA k-group
    const int qloc = lane & 31;     // q column within wave's 32-row tile

    // ---- XCD-aware decode: bid = x + 8*(r + 4*i4 + 16*g), kg = g*8+x ----
    const int bx   = blockIdx.x;
    const int chunk = bx >> 8;
    const int bidc  = bx & 255;
    const int x    = bidc & 7;
    const int rest = bidc >> 3;     // 0..31
    const int r_   = rest & 3;      // hq low bits
    const int i4   = (rest >> 2) & 3;
    const int g_   = rest >> 4;     // 0..1
    const int kg   = g_ * 8 + x;    // kv-group = b*8 + hkv
    const int b    = kg >> 3;
    const int hkv  = kg & 7;
    const int hq   = hkv * 4 + r_;
    // Chunk sets {i,15-i,4+i,11-i}: per-generation totals ~constant (R2).
    int qb;
    if      (chunk == 0) qb = i4;
    else if (chunk == 1) qb = 15 - i4;
    else if (chunk == 2) qb = 4 + i4;
    else                 qb = 11 - i4;

    const int base = qb * RPB_;
    const int row  = base + w * 32 + qloc;
    const int nt   = 4 * qb + 4;    // tile count
    const int diagt = 4 * qb + w;   // wave's diagonal tile index

    const float4* kb4 = (const float4*)K + (size_t)(b * HKV_ + hkv) * S_ * 32;
    const float4* vb4 = (const float4*)V + (size_t)b * S_ * HKV_ * 32 + hkv * 32;
    const float4* qg  = (const float4*)Q + ((size_t)(b * HQ_ + hq) * S_ + row) * 32;

    // ---- Q fragments: pre-scaled by SL2E_, fp16, hoisted (B-operand) ----
    v8h qh[8];
    #pragma unroll
    for (int ks = 0; ks < 8; ++ks) {
        float4 f0 = qg[ks * 4 + hig];
        float4 f1 = qg[ks * 4 + 2 + hig];
        v8h qv = {(_Float16)(f0.x * SL2E_), (_Float16)(f0.y * SL2E_),
                  (_Float16)(f0.z * SL2E_), (_Float16)(f0.w * SL2E_),
                  (_Float16)(f1.x * SL2E_), (_Float16)(f1.y * SL2E_),
                  (_Float16)(f1.z * SL2E_), (_Float16)(f1.w * SL2E_)};
        qh[ks] = qv;
    }

    f32x16 oacc[4];
    #pragma unroll
    for (int d = 0; d < 4; ++d)
        #pragma unroll
        for (int j = 0; j < 16; ++j) oacc[d][j] = 0.f;
    float m = NEGBIG_, lsum = 0.f;

    float4 kr[4], vr[4];
    load_k(kb4, 0, tid, kr);
    load_v(vb4, 0, tid, vr);
    store_kv(tid, kr, vr, KHI[0], VHI[0]);
    __syncthreads();

    for (int t = 0; t < nt; ++t) {
        const int bi = t & 1;
        int tn = t + 1; if (tn > nt - 1) tn = nt - 1;
        const int k0n = tn * KT_;
        const bool active = (t <= diagt);

        // 1-deep staging (locality governor): loads issued NOW, consumed by
        // store_kv after this tile's compute. Do not deepen (R5 lesson).
        load_k(kb4, k0n, tid, kr);

        float sv[16];
        if (active) {
            // ---- QK^T: S^T = K * Q^T, 8 k-steps, one b128 A-read per MFMA ----
            const _Float16* khb = KHI[bi];
            const int koff = (lane & 31) * KLD_ + 8 * hig;
            f32x16 sacc[2];
            #pragma unroll
            for (int cch = 0; cch < 2; ++cch)
                #pragma unroll
                for (int j = 0; j < 16; ++j) sacc[cch][j] = 0.f;
            __builtin_amdgcn_s_setprio(1);
            #pragma unroll
            for (int ks = 0; ks < 8; ++ks) {
                v8h ka = *(const v8h*)&khb[koff + ks * 16];
                sacc[ks & 1] = __builtin_amdgcn_mfma_f32_32x32x16_f16(ka, qh[ks], sacc[ks & 1], 0, 0, 0);
            }
            __builtin_amdgcn_s_setprio(0);
            #pragma unroll
            for (int j = 0; j < 16; ++j) sv[j] = sacc[0][j] + sacc[1][j];
        }

        load_v(vb4, k0n, tid, vr);

        if (active) {
            // ---- causal mask (diagonal tile only) ----
            if (t == diagt) {
                #pragma unroll
                for (int j = 0; j < 16; ++j) {
                    const int key = (j & 3) + 8 * (j >> 2) + 4 * hig;
                    if (key > qloc) sv[j] = NEGBIG_;
                }
            }
            // ---- online softmax: in-lane over 16 + shfl_xor(32), defer-max ----
            float mt = NEGBIG_;
            #pragma unroll
            for (int j = 0; j < 16; ++j) mt = fmaxf(mt, sv[j]);
            mt = fmaxf(mt, __shfl_xor(mt, 32));
            if (__any(mt > m + DEFER_THR_)) {
                const float mn = fmaxf(m, mt);
                const float al = exp2f(m - mn);
                m = mn;
                lsum *= al;
                #pragma unroll
                for (int d = 0; d < 4; ++d)
                    #pragma unroll
                    for (int j = 0; j < 16; ++j) oacc[d][j] *= al;
            }
            float ps = 0.f;
            #pragma unroll
            for (int j = 0; j < 16; ++j) {
                const float p = exp2f(sv[j] - m);   // bounded by 2^DEFER_THR_
                sv[j] = p;
                ps += p;
            }
            ps += __shfl_xor(ps, 32);
            lsum += ps;

            // ---- P -> fp16 B-fragments (elems j = acc regs 8h+j) ----
            v8h ph0, ph1;
            #pragma unroll
            for (int j = 0; j < 8; ++j) {
                ph0[j] = (_Float16)sv[j];
                ph1[j] = (_Float16)sv[8 + j];
            }
            // ---- PV: O^T += V^T * P^T, 4 d-subtiles x 2 key-halves ----
            const _Float16* vhb = VHI[bi];
            const int voff = (lane & 31) * VLD_ + 8 * hig;
            __builtin_amdgcn_s_setprio(1);
            #pragma unroll
            for (int d = 0; d < 4; ++d) {
                #pragma unroll
                for (int h2 = 0; h2 < 2; ++h2) {
                    v8h va = *(const v8h*)&vhb[d * 32 * VLD_ + voff + h2 * 16];
                    oacc[d] = __builtin_amdgcn_mfma_f32_32x32x16_f16(va, h2 ? ph1 : ph0, oacc[d], 0, 0, 0);
                }
            }
            __builtin_amdgcn_s_setprio(0);
        }

        store_kv(tid, kr, vr, KHI[bi ^ 1], VHI[bi ^ 1]);
        __syncthreads();   // writes of t+1 visible; all reads of tile t done
    }

    // ---- epilogue: O^T frag -> O[q][d], 4 consecutive d per reg-quad ----
    const float inv = 1.0f / lsum;
    float4* og = (float4*)O + ((size_t)(b * HQ_ + hq) * S_ + row) * 32;
    #pragma unroll
    for (int d = 0; d < 4; ++d) {
        #pragma unroll
        for (int rq = 0; rq < 4; ++rq) {
            float4 st;
            st.x = oacc[d][4 * rq + 0] * inv;
            st.y = oacc[d][4 * rq + 1] * inv;
            st.z = oacc[d][4 * rq + 2] * inv;
            st.w = oacc[d][4 * rq + 3] * inv;
            og[d * 8 + rq * 2 + hig] = st;
        }
    }
}

extern "C" void kernel_launch(void* const* d_in, const int* in_sizes, int n_in,
                              void* d_out, int out_size, void* d_ws, size_t ws_size,
                              hipStream_t stream) {
    const float* Q = (const float*)d_in[0];   // [B,HQ,S,D]
    const float* K = (const float*)d_in[1];   // [B,HKV,S,D]
    const float* V = (const float*)d_in[2];   // [B,S,Hkv,D]
    // d_in[3] (attention_mask) unused: pure causal, applied in-kernel.
    float* O = (float*)d_out;                 // [B,HQ,S,D]

    const int nblocks = (S_ / RPB_) * (B_ * HQ_);  // 16 * 64 = 1024
    fa_fwd<<<dim3(nblocks), dim3(THREADS_), 0, stream>>>(Q, K, V, O);
}

// Round 7
// 310.942 us; speedup vs baseline: 2.0992x; 1.2177x over previous
//
#include <hip/hip_runtime.h>
#include <math.h>
#include <stdint.h>

// GQA causal attention fwd, fp32 in/out, flash online-softmax, fp16 MFMA compute.
// B=2 HQ=32 HKV=8 S=2048 D=128. Mask is pure causal -> applied analytically.
//
// R7 = R6 (277 us) with 64-key staging: 2 verified 32-key sub-steps per barrier.
// Cost model from R1/R2/R6: wall = longest-chain iterations x L, L ~= 10.4k cyc
// and ~85% of L is FIXED per-iteration overhead (invariant to per-tile work and
// to fetch path: R6 cut FETCH 4.5x for -2% time; R1->R2 cut MFMAs 4.5x for -12%).
// So: halve iterations (34816 -> 17408; longest chain 64 -> 32) by staging 64
// keys per barrier, double-buffered, computing two 32-key sub-steps per tile.
// Compute core, LDS layout per 32-key half, XCD mapping, 1-deep staging
// (R5 lesson: deeper prefetch destroys L2 co-walk locality), setprio, defer-max
// all unchanged from R6.
//
// XCD mapping (R6, verified FETCH 291->65 MB): bid = x + 8*(r + 4*i4 + 16*g),
// kv-group kg = g*8+x -> all 16 blocks sharing one K/V stream land on one XCD
// (round-robin bid%8); 2 kv-groups/XCD = 4 MB K/V ~= private L2.
//
// Compute core (verified R2): swapped QK^T (A=K, B=Q) -> S^T per wave; lane owns
// q=lane&31, 16 score regs at key=(reg&3)+8*(reg>>2)+4*(lane>>5); softmax
// in-lane + shfl_xor(32); PV as O^T = V^T P^T with P already in B-fragment
// layout; d-permuted fp16 LDS (one ds_read_b128 per MFMA A-frag).

#define B_    2
#define HQ_   32
#define HKV_  8
#define S_    2048
#define D_    128
#define KT_   32              // sub-step keys (compute core granularity)
#define KT2_  64              // staged keys per barrier iteration
#define THREADS_ 256
#define RPB_  128
#define SL2E_ 0.12751743f     // (1/sqrt(128)) * log2(e)  -> softmax in exp2 domain
#define NEGBIG_ -3.0e38f
#define KLD_  136             // K row pitch in fp16 elems (128 + 8 pad, 16B-mult)
#define VLD_  72              // V^T row pitch in fp16 elems (64 + 8 pad, 16B-mult)
#define DEFER_THR_ 8.0f

typedef _Float16 v4h  __attribute__((ext_vector_type(4)));
typedef _Float16 v8h  __attribute__((ext_vector_type(8)));
typedef float    f32x16 __attribute__((ext_vector_type(16)));

__device__ __forceinline__ void load_k(const float4* kb4, int k0, int tid, float4 (&kr)[4]) {
    #pragma unroll
    for (int p = 0; p < 4; ++p)
        kr[p] = kb4[(size_t)(k0 + p * 8 + (tid >> 5)) * 32 + (tid & 31)];
}

__device__ __forceinline__ void load_v(const float4* vb4, int k0, int tid, float4 (&vr)[4]) {
    #pragma unroll
    for (int p = 0; p < 4; ++p)
        vr[p] = vb4[(size_t)(k0 + p * 8 + (tid & 7)) * (HKV_ * 32) + (tid >> 3)];
}

// regs -> LDS, one 32-key half: K row-major [32][KLD_] at kh (caller offsets
// +32*KLD_ for half 1), V transposed [128][VLD_] at vh (caller offsets +32
// columns for half 1). fp16, d-permuted within each 16-group ([0,2,1,3] quads)
// so MFMA fragments read as single b128.
__device__ __forceinline__ void store_kv(int tid, const float4 (&kr)[4], const float4 (&vr)[4],
                                         _Float16* kh, _Float16* vh) {
    const int qi  = tid & 3;
    const int c31 = tid & 31;
    const int d0p = ((c31 >> 2) << 4) | ((((c31 & 1) << 1) | ((c31 >> 1) & 1)) << 2);
    #pragma unroll
    for (int p = 0; p < 4; ++p) {
        {   // ---- K: lane covers (key = p*8 + tid>>5, d-group = tid&31) ----
            const int key = p * 8 + (tid >> 5);
            const float4 f = kr[p];
            v4h hv = {(_Float16)f.x, (_Float16)f.y, (_Float16)f.z, (_Float16)f.w};
            *(v4h*)&kh[key * KLD_ + d0p] = hv;
        }
        {   // ---- V: quad 4x4 transpose, then write 4 consecutive keys of one d-row ----
            float a0 = vr[p].x, a1 = vr[p].y, a2 = vr[p].z, a3 = vr[p].w;
            float t, r;
            t = (qi & 1) ? a0 : a1; r = __shfl_xor(t, 1);
            if (qi & 1) a0 = r; else a1 = r;
            t = (qi & 1) ? a2 : a3; r = __shfl_xor(t, 1);
            if (qi & 1) a2 = r; else a3 = r;
            t = (qi & 2) ? a0 : a2; r = __shfl_xor(t, 2);
            if (qi & 2) a0 = r; else a2 = r;
            t = (qi & 2) ? a1 : a3; r = __shfl_xor(t, 2);
            if (qi & 2) a1 = r; else a3 = r;
            const int drow = (tid >> 3) * 4 + qi;
            const int kq   = p * 8 + (tid & 4);
            const int kqp  = (kq & 16) | (((((kq >> 2) & 1) << 1) | ((kq >> 3) & 1)) << 2);
            v4h hv = {(_Float16)a0, (_Float16)a1, (_Float16)a2, (_Float16)a3};
            *(v4h*)&vh[drow * VLD_ + kqp] = hv;
        }
    }
}

// One verified 32-key compute sub-step. khb already offset to the half's K rows;
// vcol = 0 or 32 selects the half's V^T columns.
__device__ __forceinline__ void substep(
    const _Float16* khb, const _Float16* vhb, int vcol,
    const v8h (&qh)[8], f32x16 (&oacc)[4],
    float& m, float& lsum,
    int lane, int hig, int qloc, bool diag)
{
    // ---- QK^T: S^T = K * Q^T, 8 k-steps, one b128 A-read per MFMA ----
    const int koff = (lane & 31) * KLD_ + 8 * hig;
    f32x16 sacc[2];
    #pragma unroll
    for (int cch = 0; cch < 2; ++cch)
        #pragma unroll
        for (int j = 0; j < 16; ++j) sacc[cch][j] = 0.f;
    __builtin_amdgcn_s_setprio(1);
    #pragma unroll
    for (int ks = 0; ks < 8; ++ks) {
        v8h ka = *(const v8h*)&khb[koff + ks * 16];
        sacc[ks & 1] = __builtin_amdgcn_mfma_f32_32x32x16_f16(ka, qh[ks], sacc[ks & 1], 0, 0, 0);
    }
    __builtin_amdgcn_s_setprio(0);
    float sv[16];
    #pragma unroll
    for (int j = 0; j < 16; ++j) sv[j] = sacc[0][j] + sacc[1][j];

    // ---- causal mask (diagonal sub-step only) ----
    if (diag) {
        #pragma unroll
        for (int j = 0; j < 16; ++j) {
            const int key = (j & 3) + 8 * (j >> 2) + 4 * hig;
            if (key > qloc) sv[j] = NEGBIG_;
        }
    }
    // ---- online softmax: in-lane over 16 + shfl_xor(32), defer-max ----
    float mt = NEGBIG_;
    #pragma unroll
    for (int j = 0; j < 16; ++j) mt = fmaxf(mt, sv[j]);
    mt = fmaxf(mt, __shfl_xor(mt, 32));
    if (__any(mt > m + DEFER_THR_)) {
        const float mn = fmaxf(m, mt);
        const float al = exp2f(m - mn);
        m = mn;
        lsum *= al;
        #pragma unroll
        for (int d = 0; d < 4; ++d)
            #pragma unroll
            for (int j = 0; j < 16; ++j) oacc[d][j] *= al;
    }
    float ps = 0.f;
    #pragma unroll
    for (int j = 0; j < 16; ++j) {
        const float p = exp2f(sv[j] - m);   // bounded by 2^DEFER_THR_
        sv[j] = p;
        ps += p;
    }
    ps += __shfl_xor(ps, 32);
    lsum += ps;

    // ---- P -> fp16 B-fragments (elems j = acc regs 8h+j) ----
    v8h ph0, ph1;
    #pragma unroll
    for (int j = 0; j < 8; ++j) {
        ph0[j] = (_Float16)sv[j];
        ph1[j] = (_Float16)sv[8 + j];
    }
    // ---- PV: O^T += V^T * P^T, 4 d-subtiles x 2 key-halves ----
    const int voff = (lane & 31) * VLD_ + vcol + 8 * hig;
    __builtin_amdgcn_s_setprio(1);
    #pragma unroll
    for (int d = 0; d < 4; ++d) {
        #pragma unroll
        for (int h2 = 0; h2 < 2; ++h2) {
            v8h va = *(const v8h*)&vhb[d * 32 * VLD_ + voff + h2 * 16];
            oacc[d] = __builtin_amdgcn_mfma_f32_32x32x16_f16(va, h2 ? ph1 : ph0, oacc[d], 0, 0, 0);
        }
    }
    __builtin_amdgcn_s_setprio(0);
}

__global__ __launch_bounds__(THREADS_, 2)
void fa_fwd(const float* __restrict__ Q, const float* __restrict__ K,
            const float* __restrict__ V, float* __restrict__ O) {
    __shared__ _Float16 KHI[2][KT2_ * KLD_];  // 2 x 17408 B
    __shared__ _Float16 VHI[2][D_ * VLD_];    // 2 x 18432 B  -> total 71680 B

    const int tid  = threadIdx.x;
    const int lane = tid & 63;
    const int w    = tid >> 6;      // wave 0..3
    const int hig  = lane >> 5;     // MFMA k-group
    const int qloc = lane & 31;     // q column within wave's 32-row tile

    // ---- XCD-aware decode (R6): bid = x + 8*(r + 4*i4 + 16*g), kg = g*8+x ----
    const int bx   = blockIdx.x;
    const int chunk = bx >> 8;
    const int bidc  = bx & 255;
    const int x    = bidc & 7;
    const int rest = bidc >> 3;     // 0..31
    const int r_   = rest & 3;      // hq low bits
    const int i4   = (rest >> 2) & 3;
    const int g_   = rest >> 4;     // 0..1
    const int kg   = g_ * 8 + x;    // kv-group = b*8 + hkv
    const int b    = kg >> 3;
    const int hkv  = kg & 7;
    const int hq   = hkv * 4 + r_;
    // Chunk sets {i,15-i,4+i,11-i}: per-generation totals ~constant (R2).
    int qb;
    if      (chunk == 0) qb = i4;
    else if (chunk == 1) qb = 15 - i4;
    else if (chunk == 2) qb = 4 + i4;
    else                 qb = 11 - i4;

    const int base = qb * RPB_;
    const int row  = base + w * 32 + qloc;
    const int ntit = 2 * qb + 2;    // 64-key iterations
    const int diagst = 4 * qb + w;  // wave's diagonal sub-step (32-key units)

    const float4* kb4 = (const float4*)K + (size_t)(b * HKV_ + hkv) * S_ * 32;
    const float4* vb4 = (const float4*)V + (size_t)b * S_ * HKV_ * 32 + hkv * 32;
    const float4* qg  = (const float4*)Q + ((size_t)(b * HQ_ + hq) * S_ + row) * 32;

    // ---- Q fragments: pre-scaled by SL2E_, fp16, hoisted (B-operand) ----
    v8h qh[8];
    #pragma unroll
    for (int ks = 0; ks < 8; ++ks) {
        float4 f0 = qg[ks * 4 + hig];
        float4 f1 = qg[ks * 4 + 2 + hig];
        v8h qv = {(_Float16)(f0.x * SL2E_), (_Float16)(f0.y * SL2E_),
                  (_Float16)(f0.z * SL2E_), (_Float16)(f0.w * SL2E_),
                  (_Float16)(f1.x * SL2E_), (_Float16)(f1.y * SL2E_),
                  (_Float16)(f1.z * SL2E_), (_Float16)(f1.w * SL2E_)};
        qh[ks] = qv;
    }

    f32x16 oacc[4];
    #pragma unroll
    for (int d = 0; d < 4; ++d)
        #pragma unroll
        for (int j = 0; j < 16; ++j) oacc[d][j] = 0.f;
    float m = NEGBIG_, lsum = 0.f;

    float4 krA[4], krB[4], vrA[4], vrB[4];
    load_k(kb4, 0, tid, krA);  load_k(kb4, 32, tid, krB);
    load_v(vb4, 0, tid, vrA);  load_v(vb4, 32, tid, vrB);
    store_kv(tid, krA, vrA, KHI[0], VHI[0]);
    store_kv(tid, krB, vrB, KHI[0] + 32 * KLD_, VHI[0] + 32);
    __syncthreads();

    for (int t = 0; t < ntit; ++t) {
        const int bi = t & 1;
        int tn = t + 1; if (tn > ntit - 1) tn = ntit - 1;
        const int k0n = tn * KT2_;

        // 1-deep staging (locality governor, R5 lesson): issue next-tile loads
        // NOW, consumed by store_kv at end of this iteration.
        load_k(kb4, k0n, tid, krA);
        load_k(kb4, k0n + 32, tid, krB);

        // ---- sub-step 0: keys [64t, 64t+32) ----
        {
            const int gst = 2 * t;
            if (gst <= diagst)
                substep(KHI[bi], VHI[bi], 0, qh, oacc, m, lsum,
                        lane, hig, qloc, gst == diagst);
        }

        load_v(vb4, k0n, tid, vrA);
        load_v(vb4, k0n + 32, tid, vrB);

        // ---- sub-step 1: keys [64t+32, 64t+64) ----
        {
            const int gst = 2 * t + 1;
            if (gst <= diagst)
                substep(KHI[bi] + 32 * KLD_, VHI[bi], 32, qh, oacc, m, lsum,
                        lane, hig, qloc, gst == diagst);
        }

        store_kv(tid, krA, vrA, KHI[bi ^ 1], VHI[bi ^ 1]);
        store_kv(tid, krB, vrB, KHI[bi ^ 1] + 32 * KLD_, VHI[bi ^ 1] + 32);
        __syncthreads();   // writes of t+1 visible; all reads of tile t done
    }

    // ---- epilogue: O^T frag -> O[q][d], 4 consecutive d per reg-quad ----
    const float inv = 1.0f / lsum;
    float4* og = (float4*)O + ((size_t)(b * HQ_ + hq) * S_ + row) * 32;
    #pragma unroll
    for (int d = 0; d < 4; ++d) {
        #pragma unroll
        for (int rq = 0; rq < 4; ++rq) {
            float4 st;
            st.x = oacc[d][4 * rq + 0] * inv;
            st.y = oacc[d][4 * rq + 1] * inv;
            st.z = oacc[d][4 * rq + 2] * inv;
            st.w = oacc[d][4 * rq + 3] * inv;
            og[d * 8 + rq * 2 + hig] = st;
        }
    }
}

extern "C" void kernel_launch(void* const* d_in, const int* in_sizes, int n_in,
                              void* d_out, int out_size, void* d_ws, size_t ws_size,
                              hipStream_t stream) {
    const float* Q = (const float*)d_in[0];   // [B,HQ,S,D]
    const float* K = (const float*)d_in[1];   // [B,HKV,S,D]
    const float* V = (const float*)d_in[2];   // [B,S,Hkv,D]
    // d_in[3] (attention_mask) unused: pure causal, applied in-kernel.
    float* O = (float*)d_out;                 // [B,HQ,S,D]

    const int nblocks = (S_ / RPB_) * (B_ * HQ_);  // 16 * 64 = 1024
    fa_fwd<<<dim3(nblocks), dim3(THREADS_), 0, stream>>>(Q, K, V, O);
}